// Round 1
// baseline (229.953 us; speedup 1.0000x reference)
//
#include <hip/hip_runtime.h>
#include <hip/hip_bf16.h>

// HypConvHyperboloid: B=32,H=64,W=64, C_IN=65, 3x3 edge-pad conv -> HCat(577) -> Lorentz FC(255) -> time restore
// M = 131072 pixels, K = 576 (bf16 MFMA) + 1 (t_cat fp32 rank-1 in epilogue), N = 255 (pad 256)
// Round 6: counted-vmcnt triple-buffered pipeline (T4-lite). Raw s_barrier + s_waitcnt vmcnt(3)
//          keeps 2 stages (6 global_load_lds) in flight per wave -> ~2 iterations of latency cover
//          instead of the compiler's vmcnt(0) drain at every __syncthreads. setprio around MFMA (T5).
//          LDS 24K (A x3) + 48K (B x3) = 72.5KB -> still 2 blocks/CU (register file is the cap anyway:
//          64 VGPR + 64 AGPR acc = 128/wave -> 16 waves/CU).

#define CLAMP63(v) ((v) < 0 ? 0 : ((v) > 63 ? 63 : (v)))

typedef __attribute__((ext_vector_type(8))) short short8;   // 8 bf16 = 4 VGPRs
typedef __attribute__((ext_vector_type(4))) float floatx4;  // C/D frag

__device__ __forceinline__ void gl2lds16(const void* g, void* l) {
  __builtin_amdgcn_global_load_lds(
      (const __attribute__((address_space(1))) void*)g,
      (__attribute__((address_space(3))) void*)l, 16, 0, 0);
}

// ---- prep: x spatial -> bf16 pixel-major [pix][64] (16B stores); col0 -> tsq = t^2
__global__ void prep_x(const float* __restrict__ x, __hip_bfloat16* __restrict__ xs,
                       float* __restrict__ tsq) {
  int idx = blockIdx.x * 256 + threadIdx.x;   // 1048576 = 131072 pix * 8 groups
  int p = idx >> 3, g = idx & 7;
  const float* src = x + (size_t)p * 65 + 1 + g * 8;
  __align__(16) __hip_bfloat16 tmp[8];
#pragma unroll
  for (int i = 0; i < 8; ++i) tmp[i] = __float2bfloat16(src[i]);
  *(short8*)(xs + (size_t)idx * 8) = *(const short8*)tmp;
  if (g == 0) { float t = x[(size_t)p * 65]; tsq[p] = t * t; }  // same cacheline as cols 1..8
}

// ---- prep: W spatial cols -> bf16 n-major [256][576] (row 255 zero); W col0 + b -> fp32 padded
__global__ void prep_w(const float* __restrict__ W, const float* __restrict__ b,
                       __hip_bfloat16* __restrict__ Wb, float* __restrict__ Wt0,
                       float* __restrict__ bp) {
  int n = blockIdx.x;  // 256
  for (int k = threadIdx.x; k < 576; k += 256)
    Wb[n * 576 + k] = __float2bfloat16((n < 255) ? W[n * 577 + 1 + k] : 0.f);
  if (threadIdx.x == 0) {
    Wt0[n] = (n < 255) ? W[n * 577] : 0.f;
    bp[n]  = (n < 255) ? b[n] : 0.f;
  }
}

// staging for one iteration (A: 1 chunk/wave, B: 2 chunks/wave; dests wave-uniform)
#define STAGE(IT, BUF)                                                          \
  do {                                                                          \
    const int nbr_ = (IT) >> 1;                                                 \
    const int dy_ = nbr_ / 3 - 1, dx_ = nbr_ % 3 - 1;                           \
    const int c0_ = ((IT) & 1) * 32;                                            \
    int y2_ = CLAMP63(a_by + dy_);                                              \
    int x2_ = CLAMP63(a_bx + dx_);                                              \
    gl2lds16(xs + (size_t)((a_bb * 64 + y2_) * 64 + x2_) * 64 + c0_ + a_kg * 8, \
             Ab + (BUF) * 4096 + w * 512);                                      \
    _Pragma("unroll")                                                           \
    for (int j = 0; j < 2; ++j)                                                 \
      gl2lds16(b_src[j] + (IT) * 32, Bb + (BUF) * 8192 + (w * 2 + j) * 512);    \
  } while (0)

// fragment-read + 16 MFMA for buffer BC (0..2)
#define COMPUTE(BC)                                                             \
  do {                                                                          \
    const ushort* Ar = Ab + (BC) * 4096;                                        \
    const ushort* Br = Bb + (BC) * 8192;                                        \
    short8 af[4], bfr[4];                                                       \
    _Pragma("unroll")                                                           \
    for (int mf = 0; mf < 4; ++mf)                                              \
      af[mf] = *(const short8*)&Ar[(quad * 128 + m_off + mf * 16 + ln) * 8];    \
    _Pragma("unroll")                                                           \
    for (int nf = 0; nf < 4; ++nf)                                              \
      bfr[nf] = *(const short8*)&Br[(quad * 256 + n_off + nf * 16 + ln) * 8];   \
    __builtin_amdgcn_s_setprio(1);                                              \
    _Pragma("unroll")                                                           \
    for (int mf = 0; mf < 4; ++mf)                                              \
      _Pragma("unroll")                                                         \
      for (int nf = 0; nf < 4; ++nf)                                            \
        acc[mf][nf] = __builtin_amdgcn_mfma_f32_16x16x32_bf16(af[mf], bfr[nf],  \
                                                              acc[mf][nf], 0, 0, 0); \
    __builtin_amdgcn_s_setprio(0);                                              \
  } while (0)

// ---- main: M=128 x N=256 per block, BK=32, 18 iters, 8 waves (each 64x64), 3-buf LDS pipeline.
// LDS A: slot = kg*128 + m (16B slots); LDS B: slot = kg*256 + n. Frag reads = const + ln*16.
__launch_bounds__(512, 4)
__global__ void hypconv_main(const float* __restrict__ tsq,
                             const __hip_bfloat16* __restrict__ xs,
                             const __hip_bfloat16* __restrict__ Wb,
                             const float* __restrict__ Wt0,
                             const float* __restrict__ bp,
                             float* __restrict__ out) {
  __shared__ __align__(16) char smem[73728];  // A 3x8K + B 3x16K; reused: zbuf 32 x 260 f32 (33280B)
  __shared__ float tc_lds[128];
  ushort* Ab = (ushort*)smem;                 // 3 x 4096 ushort
  ushort* Bb = (ushort*)(smem + 24576);       // 3 x 8192 ushort
  float* zbuf = (float*)smem;                 // 32 rows x 260 f32

  const int tid = threadIdx.x;
  const int w = tid >> 6, lane = tid & 63;
  const int quad = lane >> 4, ln = lane & 15;
  const int pix_base = blockIdx.x * 128;
  const int m_off = (w >> 2) * 64, n_off = (w & 3) * 64;

  // A chunk: slot = w*64+lane -> kg = w>>1, m = (w&1)*64+lane
  const int a_kg = w >> 1;
  int apix = pix_base + (w & 1) * 64 + lane;
  const int a_bx = apix & 63, a_by = (apix >> 6) & 63, a_bb = apix >> 12;
  // B chunks j=0,1: slot = (w*2+j)*64+lane -> kg = (w*2+j)>>2, n = ((w*2+j)&3)*64+lane
  const __hip_bfloat16* b_src[2];
#pragma unroll
  for (int j = 0; j < 2; ++j) {
    int c = w * 2 + j;
    b_src[j] = Wb + (size_t)((c & 3) * 64 + lane) * 576 + (c >> 2) * 8;
  }

  floatx4 acc[4][4];
#pragma unroll
  for (int mf = 0; mf < 4; ++mf)
#pragma unroll
    for (int nf = 0; nf < 4; ++nf)
      acc[mf][nf] = (floatx4){0.f, 0.f, 0.f, 0.f};

  // t_cat loads FIRST: their compiler-inserted drain must not flush the staging queue
  // (tsq is 512 KB, L2-resident)
  if (tid < 128) {
    int pix = pix_base + tid;
    int bx = pix & 63, by = (pix >> 6) & 63, bb = pix >> 12;
    float s = 0.f;
#pragma unroll
    for (int dy = -1; dy <= 1; ++dy) {
      int y2 = CLAMP63(by + dy);
#pragma unroll
      for (int dx = -1; dx <= 1; ++dx) {
        int x2 = CLAMP63(bx + dx);
        s += tsq[(bb * 64 + y2) * 64 + x2];
      }
    }
    tc_lds[tid] = sqrtf(s - 8.0f);
  }

  STAGE(0, 0);  // prologue: 2 stages in flight (6 loads/wave)
  STAGE(1, 1);

  // Main pipeline. Per wave, steady state in-flight = STAGE(it) + STAGE(it+1) = 6 loads.
  // s_waitcnt vmcnt(3) retires STAGE(it) (issued TWO iterations ago) and leaves STAGE(it+1)
  // in flight across the barrier -> ~2 compute phases of latency cover (T4).
  // LDS WAR safety: STAGE(it+2) writes buf (it+2)%3 == (it-1)%3, whose ds_reads completed
  // before every wave crossed this barrier.
  int bc = 0;   // it % 3
  int bs = 2;   // (it+2) % 3
  for (int it = 0; it < 17; ++it) {
    asm volatile("s_waitcnt vmcnt(3)" ::: "memory");
    __builtin_amdgcn_s_barrier();
    __builtin_amdgcn_sched_barrier(0);
    if (it < 16) STAGE(it + 2, bs);
    COMPUTE(bc);
    bc = (bc == 2) ? 0 : bc + 1;
    bs = (bs == 2) ? 0 : bs + 1;
  }
  // final iteration (it = 17, buf 2): only STAGE(17) remains in flight
  asm volatile("s_waitcnt vmcnt(0)" ::: "memory");
  __builtin_amdgcn_s_barrier();
  __builtin_amdgcn_sched_barrier(0);
  COMPUTE(2);

  // ---- epilogue: z = acc + b[n] + t_cat[m]*W0[n]; LDS-staged (stride 260), 1KB-row flush
  __syncthreads();
  float wn[4], bnv[4];
#pragma unroll
  for (int nf = 0; nf < 4; ++nf) {
    int n = n_off + nf * 16 + ln;
    wn[nf] = Wt0[n];
    bnv[nf] = bp[n];
  }

#pragma unroll
  for (int mf = 0; mf < 4; ++mf) {
    // stage 32 rows: lr = (w>>2)*16 + quad*4 + r ; col = (1+n)&255 (z[255]=0 by padding)
#pragma unroll
    for (int r = 0; r < 4; ++r) {
      float tcv = tc_lds[m_off + mf * 16 + quad * 4 + r];
      int lr = (w >> 2) * 16 + quad * 4 + r;
#pragma unroll
      for (int nf = 0; nf < 4; ++nf) {
        float z = acc[mf][nf][r] + bnv[nf] + tcv * wn[nf];
        zbuf[lr * 260 + ((1 + n_off + nf * 16 + ln) & 255)] = z;
      }
    }
    __syncthreads();
    // flush: 8 waves x 4 rows; sum(z^2) 64-lane butterfly; t_out -> col 0
#pragma unroll
    for (int rr = 0; rr < 4; ++rr) {
      int lr = w * 4 + rr;
      float4 v = *(const float4*)&zbuf[lr * 260 + lane * 4];
      float ss = v.x * v.x + v.y * v.y + v.z * v.z + v.w * v.w;  // col0 holds z[255]=0
      ss += __shfl_xor(ss, 1, 64);
      ss += __shfl_xor(ss, 2, 64);
      ss += __shfl_xor(ss, 4, 64);
      ss += __shfl_xor(ss, 8, 64);
      ss += __shfl_xor(ss, 16, 64);
      ss += __shfl_xor(ss, 32, 64);
      float tout = sqrtf(1.0f + ss);
      if (lane == 0) v.x = tout;
      int m = (lr >> 4) * 64 + mf * 16 + (lr & 15);
      *(float4*)&out[(size_t)(pix_base + m) * 256 + lane * 4] = v;
    }
    if (mf < 3) __syncthreads();  // protect zbuf before next chunk's staging
  }
}

extern "C" void kernel_launch(void* const* d_in, const int* in_sizes, int n_in,
                              void* d_out, int out_size, void* d_ws, size_t ws_size,
                              hipStream_t stream) {
  const float* x = (const float*)d_in[0];   // (32,64,64,65)
  const float* W = (const float*)d_in[1];   // (255,577)
  const float* b = (const float*)d_in[2];   // (255,)
  float* out = (float*)d_out;               // (32,64,64,256)
  char* ws = (char*)d_ws;

  // workspace: xs 16,777,216 | Wb 294,912 | Wt0 1K | bp 1K | tsq 524,288  (~17.6 MB)
  __hip_bfloat16* xs  = (__hip_bfloat16*)(ws);
  __hip_bfloat16* Wb  = (__hip_bfloat16*)(ws + 16777216);
  float*          Wt0 = (float*)(ws + 17072128);
  float*          bp  = (float*)(ws + 17073152);
  float*          tsq = (float*)(ws + 17074176);

  prep_x<<<4096, 256, 0, stream>>>(x, xs, tsq);
  prep_w<<<256,  256, 0, stream>>>(W, b, Wb, Wt0, bp);
  hypconv_main<<<1024, 512, 0, stream>>>(tsq, xs, Wb, Wt0, bp, out);
}